// Round 5
// baseline (643.996 us; speedup 1.0000x reference)
//
#include <hip/hip_runtime.h>
#include <hip/hip_bf16.h>
#include <stdint.h>

#define EPSQ 1e-5f

typedef int i32x4 __attribute__((ext_vector_type(4)));

__device__ inline void gload16(const void* g, void* l){
  __builtin_amdgcn_global_load_lds((const __attribute__((address_space(1))) unsigned int*)g,
                                   (__attribute__((address_space(3))) unsigned int*)l, 16, 0, 0);
}

__device__ inline unsigned pack4(float4 v, float s, float lo, float hi){
  int a = (int)fminf(fmaxf(rintf(v.x*s), lo), hi);
  int b = (int)fminf(fmaxf(rintf(v.y*s), lo), hi);
  int c = (int)fminf(fmaxf(rintf(v.z*s), lo), hi);
  int d = (int)fminf(fmaxf(rintf(v.w*s), lo), hi);
  return (unsigned)((a&255)|((b&255)<<8)|((c&255)<<16)|((d&255)<<24));
}

// ---------------- mean|w| two-stage deterministic reduction ----------------
__global__ void absmean_partial(const float* __restrict__ w, int n4, double* __restrict__ partial){
  const float4* w4 = (const float4*)w;
  double s = 0.0;
  int idx = blockIdx.x*blockDim.x + threadIdx.x;
  int stride = gridDim.x*blockDim.x;
  for (int i = idx; i < n4; i += stride){
    float4 v = w4[i];
    s += (double)(fabsf(v.x)+fabsf(v.y)+fabsf(v.z)+fabsf(v.w));
  }
  __shared__ double sm[256];
  sm[threadIdx.x] = s; __syncthreads();
  for (int o=128;o>0;o>>=1){ if (threadIdx.x<o) sm[threadIdx.x]+=sm[threadIdx.x+o]; __syncthreads(); }
  if (threadIdx.x==0) partial[blockIdx.x] = sm[0];
}

__global__ void finalize_scales(const double* __restrict__ partial, float* __restrict__ scalebuf, double inv_n){
  __shared__ double sm[256];
  int t = threadIdx.x;
  double s1 = partial[t] + partial[t+256] + partial[t+512] + partial[t+768];
  sm[t]=s1; __syncthreads();
  for(int o=128;o>0;o>>=1){ if(t<o) sm[t]+=sm[t+o]; __syncthreads(); }
  double m1 = sm[0];
  __syncthreads();
  double s2 = partial[1024+t]+partial[1280+t]+partial[1536+t]+partial[1792+t];
  sm[t]=s2; __syncthreads();
  for(int o=128;o>0;o>>=1){ if(t<o) sm[t]+=sm[t+o]; __syncthreads(); }
  if (t==0){
    scalebuf[0] = 1.0f / fmaxf((float)(m1*inv_n),    EPSQ);   // s_w1
    scalebuf[1] = 1.0f / fmaxf((float)(sm[0]*inv_n), EPSQ);   // s_w2
  }
}

// ---------------- ternary weight quantization -> int8 {-1,0,1} ----------------
__global__ void wquant8(const float* __restrict__ w, char* __restrict__ wq,
                        const float* __restrict__ scalebuf, int which){
  int i = blockIdx.x*256 + threadIdx.x;
  float s = scalebuf[which];
  const float4* w4 = (const float4*)w;
  float4 v0 = w4[(size_t)i*4], v1 = w4[(size_t)i*4+1], v2 = w4[(size_t)i*4+2], v3 = w4[(size_t)i*4+3];
  uint4 pk = make_uint4(pack4(v0,s,-1.f,1.f), pack4(v1,s,-1.f,1.f),
                        pack4(v2,s,-1.f,1.f), pack4(v3,s,-1.f,1.f));
  *reinterpret_cast<uint4*>(wq + (size_t)i*16) = pk;
}

// ---------------- per-token activation quant -> int8 + scale + rowMax init ----------------
__global__ void aquant8(const float* __restrict__ x, char* __restrict__ xq,
                        float* __restrict__ s_a, int* __restrict__ rowMax){
  int m = blockIdx.x, t = threadIdx.x;           // 256 thr, D=2048
  if (t==0) rowMax[m] = 0;
  const float4* x4 = (const float4*)(x + (size_t)m*2048);
  float4 a = x4[t*2], b = x4[t*2+1];
  float va[8] = {a.x,a.y,a.z,a.w,b.x,b.y,b.z,b.w};
  float mx = 0.f;
  #pragma unroll
  for (int j=0;j<8;j++) mx = fmaxf(mx, fabsf(va[j]));
  #pragma unroll
  for (int o=1;o<64;o<<=1) mx = fmaxf(mx, __shfl_xor(mx, o, 64));
  __shared__ float wm[4];
  if ((t&63)==0) wm[t>>6] = mx;
  __syncthreads();
  mx = fmaxf(fmaxf(wm[0],wm[1]), fmaxf(wm[2],wm[3]));
  float s = 127.f / fmaxf(mx, EPSQ);
  if (t==0) s_a[m] = s;
  uint2 pk = make_uint2(pack4(a,s,-128.f,127.f), pack4(b,s,-128.f,127.f));
  *reinterpret_cast<uint2*>(xq + (size_t)m*2048 + t*8) = pk;
}

// ---------------- i8 GEMM, 128x128 tile, BK=64, depth-2 counted-vmcnt pipeline ----------------
// 3 LDS buffers; prefetch 2 K-tiles ahead; one raw s_barrier + s_waitcnt vmcnt(4) per K-step
// (never drains to 0 in the main loop -- T3/T4). setprio(1) around the MFMA cluster (T5).
// XCD-aware bijective block swizzle (T1): XCD k owns a contiguous sub-grid so its
// A/B panels (~4MB) fit the per-XCD L2.
// EPI 0: h16 = min(relu(acc),65535) + per-row int max -> rowMax. EPI 1: int32 atomicAdd into C.
template<int EPI>
__global__ __launch_bounds__(256) void gemm_i8(
    const char* __restrict__ A, int lda, const char* __restrict__ B, int ldb,
    void* __restrict__ Cv, int N, int* __restrict__ rowMax)
{
  __shared__ __align__(16) char smA[3*128*64];
  __shared__ __align__(16) char smB[3*128*64];
  __shared__ int smax[128];
  const int tid = threadIdx.x, lane = tid & 63;
  const int w = tid >> 6, wr = w >> 1, wc = w & 1;

  // XCD-aware bijective swizzle: hardware XCD = flat%8 (round-robin); give XCD k
  // the contiguous tile range nid in [k*q, (k+1)*q) decoded as (bx = nid/gy, by = nid%gy).
  const int gx = gridDim.x, gy = gridDim.y;
  const int flat = blockIdx.y*gx + blockIdx.x;
  const int q = (gx*gy) >> 3;                    // grids are multiples of 8
  const int nid = (flat & 7)*q + (flat >> 3);
  const int m0 = (nid % gy)*128, n0 = (nid / gy)*128;
  const int kbase = blockIdx.z*2048;

  i32x4 acc[4][4] = {};

  // staging: thread fills 16B chunk (srow, scl) and (srow+64, scl); 64B rows, 4 chunks/row
  const int srow = tid >> 2, scol = tid & 3;
  const int scl  = scol ^ ((srow >> 1) & 3);          // XOR swizzle via pre-swizzled source
  const char* gA = A + (size_t)(m0+srow)*lda + kbase + scl*16;
  const char* gB = B + (size_t)(n0+srow)*ldb + kbase + scl*16;
  const size_t a64 = (size_t)64*lda, b64 = (size_t)64*ldb;

  const int frow = lane & 15, kb = lane >> 4;
  const int foff = (kb ^ ((frow >> 1) & 3)) * 16;     // read-side swizzle

  auto stage = [&](int buf, int t){
    char* dA = smA + buf*8192 + tid*16;
    char* dB = smB + buf*8192 + tid*16;
    gload16(gA + t*64,       dA);
    gload16(gA + t*64 + a64, dA + 4096);
    gload16(gB + t*64,       dB);
    gload16(gB + t*64 + b64, dB + 4096);
  };

  stage(0, 0); stage(1, 1);                           // 8 loads in flight
  asm volatile("s_waitcnt vmcnt(4)" ::: "memory");    // tile 0 landed
  __builtin_amdgcn_s_barrier();
  __builtin_amdgcn_sched_barrier(0);

  int cur = 0;
  for (int t = 0; t < 32; ++t){
    if (t < 30){
      int pf = cur + 2; if (pf >= 3) pf -= 3;
      stage(pf, t+2);                                 // issue next-next tile (overlaps MFMA)
    }
    i32x4 av[4], bv[4];
    #pragma unroll
    for (int fm=0;fm<4;fm++)
      av[fm] = *reinterpret_cast<const i32x4*>(smA + cur*8192 + (wr*64+fm*16+frow)*64 + foff);
    #pragma unroll
    for (int fn=0;fn<4;fn++)
      bv[fn] = *reinterpret_cast<const i32x4*>(smB + cur*8192 + (wc*64+fn*16+frow)*64 + foff);
    __builtin_amdgcn_s_setprio(1);
    #pragma unroll
    for (int fm=0;fm<4;fm++)
      #pragma unroll
      for (int fn=0;fn<4;fn++)
        acc[fm][fn] = __builtin_amdgcn_mfma_i32_16x16x64_i8(av[fm], bv[fn], acc[fm][fn], 0,0,0);
    __builtin_amdgcn_s_setprio(0);
    if (t < 31){
      if (t < 30) asm volatile("s_waitcnt vmcnt(4)" ::: "memory");  // retire tile t+1 only
      else        asm volatile("s_waitcnt vmcnt(0)" ::: "memory");  // last prefetch drains
      __builtin_amdgcn_s_barrier();
      __builtin_amdgcn_sched_barrier(0);
    }
    cur = (cur + 1 == 3) ? 0 : cur + 1;
  }

  if (EPI == 0){
    __syncthreads();
    if (tid < 128) smax[tid] = 0;
    __syncthreads();
  }
  const int cc = lane & 15, cr = (lane >> 4)*4;
  #pragma unroll
  for (int fm=0;fm<4;fm++){
    #pragma unroll
    for (int reg=0;reg<4;reg++){
      int rl = wr*64 + fm*16 + cr + reg;
      size_t r = (size_t)(m0 + rl);
      if (EPI == 0){
        ushort* C16 = (ushort*)Cv;
        int rmax = 0;
        #pragma unroll
        for (int fn=0;fn<4;fn++){
          int v = acc[fm][fn][reg]; v = v > 0 ? v : 0;        // fused relu, exact int
          C16[r*N + n0 + wc*64 + fn*16 + cc] = (ushort)(v > 65535 ? 65535 : v);
          rmax = v > rmax ? v : rmax;
        }
        atomicMax(&smax[rl], rmax);
      } else {
        int* Ci = (int*)Cv;
        #pragma unroll
        for (int fn=0;fn<4;fn++)
          atomicAdd(&Ci[r*N + n0 + wc*64 + fn*16 + cc], acc[fm][fn][reg]);
      }
    }
  }
  if (EPI == 0){
    __syncthreads();
    if (tid < 128) atomicMax(&rowMax[m0 + tid], smax[tid]);
  }
}

// ---------------- h16 -> int8 requant (rq = 127/Mi, exact integer domain) ----------------
__global__ void hquant(const ushort* __restrict__ h16, char* __restrict__ hq,
                       const int* __restrict__ rowMax){
  int m = blockIdx.y;
  int Mi = rowMax[m];
  float rqv = (Mi > 0) ? 127.f/(float)Mi : 0.f;
  size_t base = (size_t)m*8192 + blockIdx.x*2048 + threadIdx.x*8;
  uint4 pk = *reinterpret_cast<const uint4*>(h16 + base);
  unsigned u[4] = {pk.x, pk.y, pk.z, pk.w};
  unsigned o[2] = {0,0};
  #pragma unroll
  for (int j=0;j<8;j++){
    float h = (float)(u[j>>1] >> ((j&1)*16) & 0xffff);
    int q = (int)fminf(rintf(h*rqv), 127.f);            // h >= 0
    o[j>>2] |= (unsigned)(q & 255) << ((j&3)*8);
  }
  *reinterpret_cast<uint2*>(hq + base) = make_uint2(o[0], o[1]);
}

// ---------------- int32 accum -> f32 out, per-row scale (in-place) ----------------
__global__ void convert_out(float* __restrict__ out, const int* __restrict__ rowMax,
                            const float* __restrict__ s_a, const float* __restrict__ scalebuf){
  int m = blockIdx.x, t = threadIdx.x;
  int Mi = rowMax[m];
  float maxref = (float)Mi / (s_a[m]*scalebuf[0]);
  float inv2 = fmaxf(maxref, EPSQ) / (127.f*scalebuf[1]);
  int* p = (int*)(out + (size_t)m*2048);
  int4 a = ((const int4*)p)[t*2], b = ((const int4*)p)[t*2+1];
  float4 fa = make_float4((float)a.x*inv2, (float)a.y*inv2, (float)a.z*inv2, (float)a.w*inv2);
  float4 fb = make_float4((float)b.x*inv2, (float)b.y*inv2, (float)b.z*inv2, (float)b.w*inv2);
  ((float4*)p)[t*2] = fa; ((float4*)p)[t*2+1] = fb;
}

extern "C" void kernel_launch(void* const* d_in, const int* in_sizes, int n_in,
                              void* d_out, int out_size, void* d_ws, size_t ws_size,
                              hipStream_t stream){
  const float* x  = (const float*)d_in[0];
  const float* w1 = (const float*)d_in[1];
  const float* w2 = (const float*)d_in[2];
  float* out = (float*)d_out;

  const int DIM = 2048, INNER = 8192, MTOK = 8192;
  const size_t nW = (size_t)INNER*DIM;   // 16 MB int8 per weight

  char* ws = (char*)d_ws; size_t off = 0;
  auto alloc = [&](size_t n)->char*{ char* p = ws+off; off = (off+n+255) & ~(size_t)255; return p; };

  float*  s_a     = (float*)alloc((size_t)MTOK*4);
  int*    rowMax  = (int*)  alloc((size_t)MTOK*4);
  float*  scalebuf= (float*)alloc(256);
  double* partial = (double*)alloc(2048*8);
  char*   w1q     = alloc(nW);
  char*   w2q     = alloc(nW);
  char*   a8      = alloc((size_t)MTOK*DIM);

  // chunk buffers: h16 (u16, Mc x INNER) + hq (int8, Mc x INNER)
  int Mc = 0;
  for (int m = 8192; m >= 128; m >>= 1)
    if (off + (size_t)m*INNER*3 + 1024 <= ws_size){ Mc = m; break; }
  if (!Mc) return;
  ushort* h16 = (ushort*)alloc((size_t)Mc*INNER*2);
  char*   hq  = alloc((size_t)Mc*INNER);

  absmean_partial<<<1024,256,0,stream>>>(w1, (int)(nW/4), partial);
  absmean_partial<<<1024,256,0,stream>>>(w2, (int)(nW/4), partial+1024);
  finalize_scales<<<1,256,0,stream>>>(partial, scalebuf, 1.0/(double)nW);
  wquant8<<<(int)(nW/16/256),256,0,stream>>>(w1, w1q, scalebuf, 0);
  wquant8<<<(int)(nW/16/256),256,0,stream>>>(w2, w2q, scalebuf, 1);
  aquant8<<<MTOK,256,0,stream>>>(x, a8, s_a, rowMax);

  for (int ch = 0; ch < MTOK; ch += Mc){
    // GEMM1: [Mc x 2048] x [8192 x 2048]^T -> h16, rowMax
    gemm_i8<0><<<dim3(INNER/128, Mc/128, 1),256,0,stream>>>(
        a8 + (size_t)ch*DIM, DIM, w1q, DIM, h16, INNER, rowMax + ch);
    // requant h -> int8
    hquant<<<dim3(INNER/2048, Mc),256,0,stream>>>(h16, hq, rowMax + ch);
    // GEMM2 (K-split x4, int32 atomic accumulation in d_out)
    hipMemsetAsync(out + (size_t)ch*DIM, 0, (size_t)Mc*DIM*4, stream);
    gemm_i8<1><<<dim3(DIM/128, Mc/128, INNER/2048),256,0,stream>>>(
        hq, INNER, w2q, INNER, out + (size_t)ch*DIM, DIM, nullptr);
    // scale to f32 (in-place)
    convert_out<<<Mc,256,0,stream>>>(out + (size_t)ch*DIM, rowMax + ch, s_a + ch, scalebuf);
  }
}

// Round 6
// 615.228 us; speedup vs baseline: 1.0468x; 1.0468x over previous
//
#include <hip/hip_runtime.h>
#include <hip/hip_bf16.h>
#include <stdint.h>

#define EPSQ 1e-5f

typedef int i32x4 __attribute__((ext_vector_type(4)));

__device__ inline void gload16(const void* g, void* l){
  __builtin_amdgcn_global_load_lds((const __attribute__((address_space(1))) unsigned int*)g,
                                   (__attribute__((address_space(3))) unsigned int*)l, 16, 0, 0);
}

__device__ inline unsigned pack4(float4 v, float s, float lo, float hi){
  int a = (int)fminf(fmaxf(rintf(v.x*s), lo), hi);
  int b = (int)fminf(fmaxf(rintf(v.y*s), lo), hi);
  int c = (int)fminf(fmaxf(rintf(v.z*s), lo), hi);
  int d = (int)fminf(fmaxf(rintf(v.w*s), lo), hi);
  return (unsigned)((a&255)|((b&255)<<8)|((c&255)<<16)|((d&255)<<24));
}

// ---------------- mean|w| two-stage deterministic reduction ----------------
__global__ void absmean_partial(const float* __restrict__ w, int n4, double* __restrict__ partial){
  const float4* w4 = (const float4*)w;
  double s = 0.0;
  int idx = blockIdx.x*blockDim.x + threadIdx.x;
  int stride = gridDim.x*blockDim.x;
  for (int i = idx; i < n4; i += stride){
    float4 v = w4[i];
    s += (double)(fabsf(v.x)+fabsf(v.y)+fabsf(v.z)+fabsf(v.w));
  }
  __shared__ double sm[256];
  sm[threadIdx.x] = s; __syncthreads();
  for (int o=128;o>0;o>>=1){ if (threadIdx.x<o) sm[threadIdx.x]+=sm[threadIdx.x+o]; __syncthreads(); }
  if (threadIdx.x==0) partial[blockIdx.x] = sm[0];
}

__global__ void finalize_scales(const double* __restrict__ partial, float* __restrict__ scalebuf, double inv_n){
  __shared__ double sm[256];
  int t = threadIdx.x;
  double s1 = partial[t] + partial[t+256] + partial[t+512] + partial[t+768];
  sm[t]=s1; __syncthreads();
  for(int o=128;o>0;o>>=1){ if(t<o) sm[t]+=sm[t+o]; __syncthreads(); }
  double m1 = sm[0];
  __syncthreads();
  double s2 = partial[1024+t]+partial[1280+t]+partial[1536+t]+partial[1792+t];
  sm[t]=s2; __syncthreads();
  for(int o=128;o>0;o>>=1){ if(t<o) sm[t]+=sm[t+o]; __syncthreads(); }
  if (t==0){
    scalebuf[0] = 1.0f / fmaxf((float)(m1*inv_n),    EPSQ);   // s_w1
    scalebuf[1] = 1.0f / fmaxf((float)(sm[0]*inv_n), EPSQ);   // s_w2
  }
}

// ---------------- ternary weight quantization -> int8 {-1,0,1} ----------------
__global__ void wquant8(const float* __restrict__ w, char* __restrict__ wq,
                        const float* __restrict__ scalebuf, int which){
  int i = blockIdx.x*256 + threadIdx.x;
  float s = scalebuf[which];
  const float4* w4 = (const float4*)w;
  float4 v0 = w4[(size_t)i*4], v1 = w4[(size_t)i*4+1], v2 = w4[(size_t)i*4+2], v3 = w4[(size_t)i*4+3];
  uint4 pk = make_uint4(pack4(v0,s,-1.f,1.f), pack4(v1,s,-1.f,1.f),
                        pack4(v2,s,-1.f,1.f), pack4(v3,s,-1.f,1.f));
  *reinterpret_cast<uint4*>(wq + (size_t)i*16) = pk;
}

// ---------------- per-token activation quant -> int8 + scale + rowMax init ----------------
__global__ void aquant8(const float* __restrict__ x, char* __restrict__ xq,
                        float* __restrict__ s_a, int* __restrict__ rowMax){
  int m = blockIdx.x, t = threadIdx.x;           // 256 thr, D=2048
  if (t==0) rowMax[m] = 0;
  const float4* x4 = (const float4*)(x + (size_t)m*2048);
  float4 a = x4[t*2], b = x4[t*2+1];
  float va[8] = {a.x,a.y,a.z,a.w,b.x,b.y,b.z,b.w};
  float mx = 0.f;
  #pragma unroll
  for (int j=0;j<8;j++) mx = fmaxf(mx, fabsf(va[j]));
  #pragma unroll
  for (int o=1;o<64;o<<=1) mx = fmaxf(mx, __shfl_xor(mx, o, 64));
  __shared__ float wm[4];
  if ((t&63)==0) wm[t>>6] = mx;
  __syncthreads();
  mx = fmaxf(fmaxf(wm[0],wm[1]), fmaxf(wm[2],wm[3]));
  float s = 127.f / fmaxf(mx, EPSQ);
  if (t==0) s_a[m] = s;
  uint2 pk = make_uint2(pack4(a,s,-128.f,127.f), pack4(b,s,-128.f,127.f));
  *reinterpret_cast<uint2*>(xq + (size_t)m*2048 + t*8) = pk;
}

// ---------------- i8 GEMM, 128x128 tile, BK=64, depth-2 counted-vmcnt pipeline ----------------
// 3 LDS buffers, STATIC indices (loop unrolled 3x: 10 x {buf0,buf1,buf2} + tail 30,31).
// Prefetch 2 K-tiles ahead; per K-step: one raw s_barrier + s_waitcnt vmcnt(4)
// (never drains to 0 in the main loop -- T4). setprio(1) around the MFMA cluster (T5).
// No XCD swizzle (round-5 A/B: it doubled L2-miss traffic).
// EPI 0: h16 = min(relu(acc),65535) + per-row int max -> rowMax. EPI 1: int32 atomicAdd into C.
template<int EPI>
__global__ __launch_bounds__(256) void gemm_i8(
    const char* __restrict__ A, int lda, const char* __restrict__ B, int ldb,
    void* __restrict__ Cv, int N, int* __restrict__ rowMax)
{
  __shared__ __align__(16) char smA[3*128*64];
  __shared__ __align__(16) char smB[3*128*64];
  __shared__ int smax[128];
  const int tid = threadIdx.x, lane = tid & 63;
  const int w = tid >> 6, wr = w >> 1, wc = w & 1;
  const int m0 = blockIdx.y*128, n0 = blockIdx.x*128;
  const int kbase = blockIdx.z*2048;

  i32x4 acc[4][4] = {};

  // staging: thread fills 16B chunk (srow, scl) and (srow+64, scl); 64B rows, 4 chunks/row
  const int srow = tid >> 2, scol = tid & 3;
  const int scl  = scol ^ ((srow >> 1) & 3);          // XOR swizzle via pre-swizzled source
  const char* gA = A + (size_t)(m0+srow)*lda + kbase + scl*16;
  const char* gB = B + (size_t)(n0+srow)*ldb + kbase + scl*16;
  const size_t a64 = (size_t)64*lda, b64 = (size_t)64*ldb;

  const int frow = lane & 15, kb = lane >> 4;
  const int foff = (kb ^ ((frow >> 1) & 3)) * 16;     // read-side swizzle

  // per-thread constant LDS offsets (buf*8192 added as an immediate at each call site)
  int aoff[4], boff[4];
  #pragma unroll
  for (int f=0;f<4;f++){
    aoff[f] = (wr*64+f*16+frow)*64 + foff;
    boff[f] = (wc*64+f*16+frow)*64 + foff;
  }
  const int doff = tid*16;

  auto stage = [&](int buf, int t){                   // buf literal at every call site
    char* dA = smA + buf*8192 + doff;
    char* dB = smB + buf*8192 + doff;
    gload16(gA + t*64,       dA);
    gload16(gA + t*64 + a64, dA + 4096);
    gload16(gB + t*64,       dB);
    gload16(gB + t*64 + b64, dB + 4096);
  };

  auto kstep = [&](int buf, int t, int mode){         // mode 0: stage+wait4, 1: wait0, 2: none
    if (mode == 0){
      int pf = buf + 2; if (pf >= 3) pf -= 3;         // folds: buf is a literal
      stage(pf, t + 2);
    }
    i32x4 av[4], bv[4];
    #pragma unroll
    for (int fm=0;fm<4;fm++)
      av[fm] = *reinterpret_cast<const i32x4*>(smA + buf*8192 + aoff[fm]);
    #pragma unroll
    for (int fn=0;fn<4;fn++)
      bv[fn] = *reinterpret_cast<const i32x4*>(smB + buf*8192 + boff[fn]);
    __builtin_amdgcn_s_setprio(1);
    #pragma unroll
    for (int fm=0;fm<4;fm++)
      #pragma unroll
      for (int fn=0;fn<4;fn++)
        acc[fm][fn] = __builtin_amdgcn_mfma_i32_16x16x64_i8(av[fm], bv[fn], acc[fm][fn], 0,0,0);
    __builtin_amdgcn_s_setprio(0);
    if (mode == 0)      asm volatile("s_waitcnt vmcnt(4)" ::: "memory");
    else if (mode == 1) asm volatile("s_waitcnt vmcnt(0)" ::: "memory");
    if (mode != 2){
      __builtin_amdgcn_s_barrier();
      __builtin_amdgcn_sched_barrier(0);
    }
  };

  stage(0, 0); stage(1, 1);                           // 8 loads in flight
  asm volatile("s_waitcnt vmcnt(4)" ::: "memory");    // tile 0 landed
  __builtin_amdgcn_s_barrier();
  __builtin_amdgcn_sched_barrier(0);

  for (int tt = 0; tt < 30; tt += 3){                 // static buffer rotation
    kstep(0, tt,   0);
    kstep(1, tt+1, 0);
    kstep(2, tt+2, 0);
  }
  kstep(0, 30, 1);                                    // last prefetch (tile 31) drains
  kstep(1, 31, 2);

  if (EPI == 0){
    __syncthreads();
    if (tid < 128) smax[tid] = 0;
    __syncthreads();
  }
  const int cc = lane & 15, cr = (lane >> 4)*4;
  #pragma unroll
  for (int fm=0;fm<4;fm++){
    #pragma unroll
    for (int reg=0;reg<4;reg++){
      int rl = wr*64 + fm*16 + cr + reg;
      size_t r = (size_t)(m0 + rl);
      if (EPI == 0){
        ushort* C16 = (ushort*)Cv;
        int rmax = 0;
        #pragma unroll
        for (int fn=0;fn<4;fn++){
          int v = acc[fm][fn][reg]; v = v > 0 ? v : 0;        // fused relu, exact int
          C16[r*N + n0 + wc*64 + fn*16 + cc] = (ushort)(v > 65535 ? 65535 : v);
          rmax = v > rmax ? v : rmax;
        }
        atomicMax(&smax[rl], rmax);
      } else {
        int* Ci = (int*)Cv;
        #pragma unroll
        for (int fn=0;fn<4;fn++)
          atomicAdd(&Ci[r*N + n0 + wc*64 + fn*16 + cc], acc[fm][fn][reg]);
      }
    }
  }
  if (EPI == 0){
    __syncthreads();
    if (tid < 128) atomicMax(&rowMax[m0 + tid], smax[tid]);
  }
}

// ---------------- h16 -> int8 requant (rq = 127/Mi, exact integer domain) ----------------
__global__ void hquant(const ushort* __restrict__ h16, char* __restrict__ hq,
                       const int* __restrict__ rowMax){
  int m = blockIdx.y;
  int Mi = rowMax[m];
  float rqv = (Mi > 0) ? 127.f/(float)Mi : 0.f;
  size_t base = (size_t)m*8192 + blockIdx.x*2048 + threadIdx.x*8;
  uint4 pk = *reinterpret_cast<const uint4*>(h16 + base);
  unsigned u[4] = {pk.x, pk.y, pk.z, pk.w};
  unsigned o[2] = {0,0};
  #pragma unroll
  for (int j=0;j<8;j++){
    float h = (float)(u[j>>1] >> ((j&1)*16) & 0xffff);
    int q = (int)fminf(rintf(h*rqv), 127.f);            // h >= 0
    o[j>>2] |= (unsigned)(q & 255) << ((j&3)*8);
  }
  *reinterpret_cast<uint2*>(hq + base) = make_uint2(o[0], o[1]);
}

// ---------------- int32 accum -> f32 out, per-row scale (in-place) ----------------
__global__ void convert_out(float* __restrict__ out, const int* __restrict__ rowMax,
                            const float* __restrict__ s_a, const float* __restrict__ scalebuf){
  int m = blockIdx.x, t = threadIdx.x;
  int Mi = rowMax[m];
  float maxref = (float)Mi / (s_a[m]*scalebuf[0]);
  float inv2 = fmaxf(maxref, EPSQ) / (127.f*scalebuf[1]);
  int* p = (int*)(out + (size_t)m*2048);
  int4 a = ((const int4*)p)[t*2], b = ((const int4*)p)[t*2+1];
  float4 fa = make_float4((float)a.x*inv2, (float)a.y*inv2, (float)a.z*inv2, (float)a.w*inv2);
  float4 fb = make_float4((float)b.x*inv2, (float)b.y*inv2, (float)b.z*inv2, (float)b.w*inv2);
  ((float4*)p)[t*2] = fa; ((float4*)p)[t*2+1] = fb;
}

extern "C" void kernel_launch(void* const* d_in, const int* in_sizes, int n_in,
                              void* d_out, int out_size, void* d_ws, size_t ws_size,
                              hipStream_t stream){
  const float* x  = (const float*)d_in[0];
  const float* w1 = (const float*)d_in[1];
  const float* w2 = (const float*)d_in[2];
  float* out = (float*)d_out;

  const int DIM = 2048, INNER = 8192, MTOK = 8192;
  const size_t nW = (size_t)INNER*DIM;   // 16 MB int8 per weight

  char* ws = (char*)d_ws; size_t off = 0;
  auto alloc = [&](size_t n)->char*{ char* p = ws+off; off = (off+n+255) & ~(size_t)255; return p; };

  float*  s_a     = (float*)alloc((size_t)MTOK*4);
  int*    rowMax  = (int*)  alloc((size_t)MTOK*4);
  float*  scalebuf= (float*)alloc(256);
  double* partial = (double*)alloc(2048*8);
  char*   w1q     = alloc(nW);
  char*   w2q     = alloc(nW);
  char*   a8      = alloc((size_t)MTOK*DIM);

  // chunk buffers: h16 (u16, Mc x INNER) + hq (int8, Mc x INNER)
  int Mc = 0;
  for (int m = 8192; m >= 128; m >>= 1)
    if (off + (size_t)m*INNER*3 + 1024 <= ws_size){ Mc = m; break; }
  if (!Mc) return;
  ushort* h16 = (ushort*)alloc((size_t)Mc*INNER*2);
  char*   hq  = alloc((size_t)Mc*INNER);

  absmean_partial<<<1024,256,0,stream>>>(w1, (int)(nW/4), partial);
  absmean_partial<<<1024,256,0,stream>>>(w2, (int)(nW/4), partial+1024);
  finalize_scales<<<1,256,0,stream>>>(partial, scalebuf, 1.0/(double)nW);
  wquant8<<<(int)(nW/16/256),256,0,stream>>>(w1, w1q, scalebuf, 0);
  wquant8<<<(int)(nW/16/256),256,0,stream>>>(w2, w2q, scalebuf, 1);
  aquant8<<<MTOK,256,0,stream>>>(x, a8, s_a, rowMax);

  for (int ch = 0; ch < MTOK; ch += Mc){
    // GEMM1: [Mc x 2048] x [8192 x 2048]^T -> h16, rowMax
    gemm_i8<0><<<dim3(INNER/128, Mc/128, 1),256,0,stream>>>(
        a8 + (size_t)ch*DIM, DIM, w1q, DIM, h16, INNER, rowMax + ch);
    // requant h -> int8
    hquant<<<dim3(INNER/2048, Mc),256,0,stream>>>(h16, hq, rowMax + ch);
    // GEMM2 (K-split x4, int32 atomic accumulation in d_out)
    hipMemsetAsync(out + (size_t)ch*DIM, 0, (size_t)Mc*DIM*4, stream);
    gemm_i8<1><<<dim3(DIM/128, Mc/128, INNER/2048),256,0,stream>>>(
        hq, INNER, w2q, INNER, out + (size_t)ch*DIM, DIM, nullptr);
    // scale to f32 (in-place)
    convert_out<<<Mc,256,0,stream>>>(out + (size_t)ch*DIM, rowMax + ch, s_a + ch, scalebuf);
  }
}

// Round 7
// 586.420 us; speedup vs baseline: 1.0982x; 1.0491x over previous
//
#include <hip/hip_runtime.h>
#include <hip/hip_bf16.h>
#include <stdint.h>

#define EPSQ 1e-5f

typedef int i32x4 __attribute__((ext_vector_type(4)));

__device__ inline void gload16(const void* g, void* l){
  __builtin_amdgcn_global_load_lds((const __attribute__((address_space(1))) unsigned int*)g,
                                   (__attribute__((address_space(3))) unsigned int*)l, 16, 0, 0);
}

__device__ inline unsigned pack4(float4 v, float s, float lo, float hi){
  int a = (int)fminf(fmaxf(rintf(v.x*s), lo), hi);
  int b = (int)fminf(fmaxf(rintf(v.y*s), lo), hi);
  int c = (int)fminf(fmaxf(rintf(v.z*s), lo), hi);
  int d = (int)fminf(fmaxf(rintf(v.w*s), lo), hi);
  return (unsigned)((a&255)|((b&255)<<8)|((c&255)<<16)|((d&255)<<24));
}

// ---------------- mean|w| two-stage deterministic reduction ----------------
__global__ void absmean_partial(const float* __restrict__ w, int n4, double* __restrict__ partial){
  const float4* w4 = (const float4*)w;
  double s = 0.0;
  int idx = blockIdx.x*blockDim.x + threadIdx.x;
  int stride = gridDim.x*blockDim.x;
  for (int i = idx; i < n4; i += stride){
    float4 v = w4[i];
    s += (double)(fabsf(v.x)+fabsf(v.y)+fabsf(v.z)+fabsf(v.w));
  }
  __shared__ double sm[256];
  sm[threadIdx.x] = s; __syncthreads();
  for (int o=128;o>0;o>>=1){ if (threadIdx.x<o) sm[threadIdx.x]+=sm[threadIdx.x+o]; __syncthreads(); }
  if (threadIdx.x==0) partial[blockIdx.x] = sm[0];
}

__global__ void finalize_scales(const double* __restrict__ partial, float* __restrict__ scalebuf, double inv_n){
  __shared__ double sm[256];
  int t = threadIdx.x;
  double s1 = partial[t] + partial[t+256] + partial[t+512] + partial[t+768];
  sm[t]=s1; __syncthreads();
  for(int o=128;o>0;o>>=1){ if(t<o) sm[t]+=sm[t+o]; __syncthreads(); }
  double m1 = sm[0];
  __syncthreads();
  double s2 = partial[1024+t]+partial[1280+t]+partial[1536+t]+partial[1792+t];
  sm[t]=s2; __syncthreads();
  for(int o=128;o>0;o>>=1){ if(t<o) sm[t]+=sm[t+o]; __syncthreads(); }
  if (t==0){
    scalebuf[0] = 1.0f / fmaxf((float)(m1*inv_n),    EPSQ);   // s_w1
    scalebuf[1] = 1.0f / fmaxf((float)(sm[0]*inv_n), EPSQ);   // s_w2
  }
}

// ---------------- ternary weight quantization -> int8 {-1,0,1} ----------------
__global__ void wquant8(const float* __restrict__ w, char* __restrict__ wq,
                        const float* __restrict__ scalebuf, int which){
  int i = blockIdx.x*256 + threadIdx.x;
  float s = scalebuf[which];
  const float4* w4 = (const float4*)w;
  float4 v0 = w4[(size_t)i*4], v1 = w4[(size_t)i*4+1], v2 = w4[(size_t)i*4+2], v3 = w4[(size_t)i*4+3];
  uint4 pk = make_uint4(pack4(v0,s,-1.f,1.f), pack4(v1,s,-1.f,1.f),
                        pack4(v2,s,-1.f,1.f), pack4(v3,s,-1.f,1.f));
  *reinterpret_cast<uint4*>(wq + (size_t)i*16) = pk;
}

// ---------------- per-token activation quant -> int8 + scale + rowMax init ----------------
__global__ void aquant8(const float* __restrict__ x, char* __restrict__ xq,
                        float* __restrict__ s_a, int* __restrict__ rowMax){
  int m = blockIdx.x, t = threadIdx.x;           // 256 thr, D=2048
  if (t==0) rowMax[m] = 0;
  const float4* x4 = (const float4*)(x + (size_t)m*2048);
  float4 a = x4[t*2], b = x4[t*2+1];
  float va[8] = {a.x,a.y,a.z,a.w,b.x,b.y,b.z,b.w};
  float mx = 0.f;
  #pragma unroll
  for (int j=0;j<8;j++) mx = fmaxf(mx, fabsf(va[j]));
  #pragma unroll
  for (int o=1;o<64;o<<=1) mx = fmaxf(mx, __shfl_xor(mx, o, 64));
  __shared__ float wm[4];
  if ((t&63)==0) wm[t>>6] = mx;
  __syncthreads();
  mx = fmaxf(fmaxf(wm[0],wm[1]), fmaxf(wm[2],wm[3]));
  float s = 127.f / fmaxf(mx, EPSQ);
  if (t==0) s_a[m] = s;
  uint2 pk = make_uint2(pack4(a,s,-128.f,127.f), pack4(b,s,-128.f,127.f));
  *reinterpret_cast<uint2*>(xq + (size_t)m*2048 + t*8) = pk;
}

// ---------------- i8 GEMM: 128x128 tile, BK=128 (m97 byte-geometry), single-buffer ----------------
// LDS rows are 128B (8 x 16B chunks), XOR swizzle chunk^(row&7) (involution; pre-swizzled
// global source + linear LDS dest + swizzled read). 2 barriers per K-step, 32 MFMA/step,
// 8 global_load_lds(16B)/thread/step, K=2048 per dispatch (16 steps).
// Band-4 m-swizzle: consecutive flat blocks sweep n fastest within a 4-m-row band
// (preserves default dispatch locality, cuts B-panel refetch 4x).
// EPI 0: h16 = min(relu(acc),65535) + per-row int max -> rowMax. EPI 1: int32 atomicAdd into C.
template<int EPI>
__global__ __launch_bounds__(256) void gemm_i8(
    const char* __restrict__ A, int lda, const char* __restrict__ B, int ldb,
    void* __restrict__ Cv, int N, int* __restrict__ rowMax)
{
  __shared__ __align__(16) char smA[128*128];
  __shared__ __align__(16) char smB[128*128];
  __shared__ int smax[128];
  const int tid = threadIdx.x, lane = tid & 63;
  const int w = tid >> 6, wr = w >> 1, wc = w & 1;

  int bx, by;
  if ((gridDim.y & 3) == 0){
    int gx = gridDim.x;
    int flat = blockIdx.y*gx + blockIdx.x;
    int per = gx << 2;
    int band = flat / per, i = flat - band*per;
    bx = i % gx; by = (band << 2) + i / gx;
  } else { bx = blockIdx.x; by = blockIdx.y; }
  const int m0 = by*128, n0 = bx*128;
  const int kbase = blockIdx.z*2048;

  i32x4 acc[4][4] = {};

  // staging geometry: chunk id p = i*256+tid (i=0..3); row = p>>3 = i*32 + (tid>>3);
  // phys slot p holds logical chunk (p&7)^(row&7) -> source column cl*16
  const int pr = tid >> 3;
  const int cl = (tid & 7) ^ (pr & 7);
  const char* gA = A + (size_t)(m0 + pr)*lda + kbase + cl*16;
  const char* gB = B + (size_t)(n0 + pr)*ldb + kbase + cl*16;

  // read-side: frag row = (wave block)+frow, logical chunk c = ks*4+kb, phys = c^(frow&7)
  const int frow = lane & 15, kb = lane >> 4;

  for (int kt = 0; kt < 2048; kt += 128){
    __syncthreads();                                  // WAR: previous step's reads done
    #pragma unroll
    for (int i=0;i<4;i++){
      gload16(gA + (size_t)(i*32)*lda + kt, smA + (i*256+tid)*16);
      gload16(gB + (size_t)(i*32)*ldb + kt, smB + (i*256+tid)*16);
    }
    __syncthreads();                                  // compiler drains vmcnt before barrier
    #pragma unroll
    for (int ks=0; ks<2; ks++){
      const int foff = (((ks<<2)|kb) ^ (frow & 7)) * 16;
      i32x4 av[4], bv[4];
      #pragma unroll
      for (int fm=0;fm<4;fm++)
        av[fm] = *reinterpret_cast<const i32x4*>(smA + (wr*64+fm*16+frow)*128 + foff);
      #pragma unroll
      for (int fn=0;fn<4;fn++)
        bv[fn] = *reinterpret_cast<const i32x4*>(smB + (wc*64+fn*16+frow)*128 + foff);
      #pragma unroll
      for (int fm=0;fm<4;fm++)
        #pragma unroll
        for (int fn=0;fn<4;fn++)
          acc[fm][fn] = __builtin_amdgcn_mfma_i32_16x16x64_i8(av[fm], bv[fn], acc[fm][fn], 0,0,0);
    }
  }

  if (EPI == 0){
    __syncthreads();
    if (tid < 128) smax[tid] = 0;
    __syncthreads();
  }
  const int cc = lane & 15, cr = (lane >> 4)*4;
  #pragma unroll
  for (int fm=0;fm<4;fm++){
    #pragma unroll
    for (int reg=0;reg<4;reg++){
      int rl = wr*64 + fm*16 + cr + reg;
      size_t r = (size_t)(m0 + rl);
      if (EPI == 0){
        ushort* C16 = (ushort*)Cv;
        int rmax = 0;
        #pragma unroll
        for (int fn=0;fn<4;fn++){
          int v = acc[fm][fn][reg]; v = v > 0 ? v : 0;        // fused relu, exact int
          C16[r*N + n0 + wc*64 + fn*16 + cc] = (ushort)(v > 65535 ? 65535 : v);
          rmax = v > rmax ? v : rmax;
        }
        atomicMax(&smax[rl], rmax);
      } else {
        int* Ci = (int*)Cv;
        #pragma unroll
        for (int fn=0;fn<4;fn++)
          atomicAdd(&Ci[r*N + n0 + wc*64 + fn*16 + cc], acc[fm][fn][reg]);
      }
    }
  }
  if (EPI == 0){
    __syncthreads();
    if (tid < 128) atomicMax(&rowMax[m0 + tid], smax[tid]);
  }
}

// ---------------- h16 -> int8 requant (rq = 127/Mi, exact integer domain) ----------------
__global__ void hquant(const ushort* __restrict__ h16, char* __restrict__ hq,
                       const int* __restrict__ rowMax){
  int m = blockIdx.y;
  int Mi = rowMax[m];
  float rqv = (Mi > 0) ? 127.f/(float)Mi : 0.f;
  size_t base = (size_t)m*8192 + blockIdx.x*2048 + threadIdx.x*8;
  uint4 pk = *reinterpret_cast<const uint4*>(h16 + base);
  unsigned u[4] = {pk.x, pk.y, pk.z, pk.w};
  unsigned o[2] = {0,0};
  #pragma unroll
  for (int j=0;j<8;j++){
    float h = (float)(u[j>>1] >> ((j&1)*16) & 0xffff);
    int q = (int)fminf(rintf(h*rqv), 127.f);            // h >= 0
    o[j>>2] |= (unsigned)(q & 255) << ((j&3)*8);
  }
  *reinterpret_cast<uint2*>(hq + base) = make_uint2(o[0], o[1]);
}

// ---------------- int32 accum -> f32 out, per-row scale (in-place) ----------------
__global__ void convert_out(float* __restrict__ out, const int* __restrict__ rowMax,
                            const float* __restrict__ s_a, const float* __restrict__ scalebuf){
  int m = blockIdx.x, t = threadIdx.x;
  int Mi = rowMax[m];
  float maxref = (float)Mi / (s_a[m]*scalebuf[0]);
  float inv2 = fmaxf(maxref, EPSQ) / (127.f*scalebuf[1]);
  int* p = (int*)(out + (size_t)m*2048);
  int4 a = ((const int4*)p)[t*2], b = ((const int4*)p)[t*2+1];
  float4 fa = make_float4((float)a.x*inv2, (float)a.y*inv2, (float)a.z*inv2, (float)a.w*inv2);
  float4 fb = make_float4((float)b.x*inv2, (float)b.y*inv2, (float)b.z*inv2, (float)b.w*inv2);
  ((float4*)p)[t*2] = fa; ((float4*)p)[t*2+1] = fb;
}

extern "C" void kernel_launch(void* const* d_in, const int* in_sizes, int n_in,
                              void* d_out, int out_size, void* d_ws, size_t ws_size,
                              hipStream_t stream){
  const float* x  = (const float*)d_in[0];
  const float* w1 = (const float*)d_in[1];
  const float* w2 = (const float*)d_in[2];
  float* out = (float*)d_out;

  const int DIM = 2048, INNER = 8192, MTOK = 8192;
  const size_t nW = (size_t)INNER*DIM;   // 16 MB int8 per weight

  char* ws = (char*)d_ws; size_t off = 0;
  auto alloc = [&](size_t n)->char*{ char* p = ws+off; off = (off+n+255) & ~(size_t)255; return p; };

  float*  s_a     = (float*)alloc((size_t)MTOK*4);
  int*    rowMax  = (int*)  alloc((size_t)MTOK*4);
  float*  scalebuf= (float*)alloc(256);
  double* partial = (double*)alloc(2048*8);
  char*   w1q     = alloc(nW);
  char*   w2q     = alloc(nW);
  char*   a8      = alloc((size_t)MTOK*DIM);

  // chunk buffers: h16 (u16, Mc x INNER) + hq (int8, Mc x INNER)
  int Mc = 0;
  for (int m = 8192; m >= 128; m >>= 1)
    if (off + (size_t)m*INNER*3 + 1024 <= ws_size){ Mc = m; break; }
  if (!Mc) return;
  ushort* h16 = (ushort*)alloc((size_t)Mc*INNER*2);
  char*   hq  = alloc((size_t)Mc*INNER);

  absmean_partial<<<1024,256,0,stream>>>(w1, (int)(nW/4), partial);
  absmean_partial<<<1024,256,0,stream>>>(w2, (int)(nW/4), partial+1024);
  finalize_scales<<<1,256,0,stream>>>(partial, scalebuf, 1.0/(double)nW);
  wquant8<<<(int)(nW/16/256),256,0,stream>>>(w1, w1q, scalebuf, 0);
  wquant8<<<(int)(nW/16/256),256,0,stream>>>(w2, w2q, scalebuf, 1);
  aquant8<<<MTOK,256,0,stream>>>(x, a8, s_a, rowMax);

  for (int ch = 0; ch < MTOK; ch += Mc){
    // GEMM1: [Mc x 2048] x [8192 x 2048]^T -> h16, rowMax
    gemm_i8<0><<<dim3(INNER/128, Mc/128, 1),256,0,stream>>>(
        a8 + (size_t)ch*DIM, DIM, w1q, DIM, h16, INNER, rowMax + ch);
    // requant h -> int8
    hquant<<<dim3(INNER/2048, Mc),256,0,stream>>>(h16, hq, rowMax + ch);
    // GEMM2 (K-split x4, int32 atomic accumulation in d_out)
    hipMemsetAsync(out + (size_t)ch*DIM, 0, (size_t)Mc*DIM*4, stream);
    gemm_i8<1><<<dim3(DIM/128, Mc/128, INNER/2048),256,0,stream>>>(
        hq, INNER, w2q, INNER, out + (size_t)ch*DIM, DIM, nullptr);
    // scale to f32 (in-place)
    convert_out<<<Mc,256,0,stream>>>(out + (size_t)ch*DIM, rowMax + ch, s_a + ch, scalebuf);
  }
}